// Round 4
// baseline (161.724 us; speedup 1.0000x reference)
//
#include <hip/hip_runtime.h>

// out[b,s,f] = in1[b,s,f] * w[f] + in2[b,s,f] * (1 - w[f])
// B=4, S=4096, F=4096 -> 67,108,864 f32 = 16,777,216 vec4. Memory-bound.
//
// R3 post-mortem: 139.6 us = ~60% of HBM roofline (524 MB actual HBM traffic,
// floor ~83 us). One-burst-per-block left no loads in flight during
// compute/store, and 16384-block turnover added overhead.
//
// R4: 2048 blocks x 8 rows each, explicit 2-stage register pipeline:
//   stage = half-row (512 vec4, thread t covers {t, t+256} within the half).
//   While stage s computes/stores, stage s+1's 4 loads are already in flight
//   (compiler emits partial vmcnt waits: older loads complete first).
// Named regs only (no runtime indexing -> no scratch), #pragma unroll 1 to
// keep VGPR near 64 (occupancy cliff at 64/128). Weights loaded once/block.

typedef float fvec4 __attribute__((ext_vector_type(4)));

__global__ __launch_bounds__(256) void merger_kernel(
    const fvec4* __restrict__ a,
    const fvec4* __restrict__ b,
    const fvec4* __restrict__ w,
    fvec4* __restrict__ out) {
    const int t = threadIdx.x;
    const int base = blockIdx.x * 8192 + t;  // 8 rows of 1024 vec4 per block

    // One feature row = 1024 vec4; weight index = position-in-row.
    // Even stage (half 0): offsets {t, t+256}; odd stage (half 1): {t+512, t+768}.
    const fvec4 w0 = w[t];
    const fvec4 w1 = w[t + 256];
    const fvec4 w2 = w[t + 512];
    const fvec4 w3 = w[t + 768];

    fvec4 A0, A1, A2, A3;  // even-stage data (a,a,b,b)
    fvec4 B0, B1, B2, B3;  // odd-stage data

    // Prologue: load even stage of row 0.
    A0 = a[base];
    A1 = a[base + 256];
    A2 = b[base];
    A3 = b[base + 256];

#pragma unroll 1
    for (int k = 0; k < 7; ++k) {
        const int e = base + k * 1024;  // even-stage base (half 0 of row k)
        const int o = e + 512;          // odd-stage base  (half 1 of row k)

        // Issue odd-stage loads before consuming even-stage regs.
        B0 = a[o];
        B1 = a[o + 256];
        B2 = b[o];
        B3 = b[o + 256];

        // Compute + store even stage (waits only on the older A-loads).
        fvec4 r0 = A0 * w0 + A2 * (1.0f - w0);
        fvec4 r1 = A1 * w1 + A3 * (1.0f - w1);
        __builtin_nontemporal_store(r0, &out[e]);
        __builtin_nontemporal_store(r1, &out[e + 256]);

        // Issue next row's even-stage loads before consuming odd-stage regs.
        const int e2 = e + 1024;
        A0 = a[e2];
        A1 = a[e2 + 256];
        A2 = b[e2];
        A3 = b[e2 + 256];

        // Compute + store odd stage.
        fvec4 r2 = B0 * w2 + B2 * (1.0f - w2);
        fvec4 r3 = B1 * w3 + B3 * (1.0f - w3);
        __builtin_nontemporal_store(r2, &out[o]);
        __builtin_nontemporal_store(r3, &out[o + 256]);
    }

    // Tail: row 7 (A already holds its even stage).
    {
        const int e = base + 7 * 1024;
        const int o = e + 512;
        B0 = a[o];
        B1 = a[o + 256];
        B2 = b[o];
        B3 = b[o + 256];

        fvec4 r0 = A0 * w0 + A2 * (1.0f - w0);
        fvec4 r1 = A1 * w1 + A3 * (1.0f - w1);
        __builtin_nontemporal_store(r0, &out[e]);
        __builtin_nontemporal_store(r1, &out[e + 256]);

        fvec4 r2 = B0 * w2 + B2 * (1.0f - w2);
        fvec4 r3 = B1 * w3 + B3 * (1.0f - w3);
        __builtin_nontemporal_store(r2, &out[o]);
        __builtin_nontemporal_store(r3, &out[o + 256]);
    }
}

extern "C" void kernel_launch(void* const* d_in, const int* in_sizes, int n_in,
                              void* d_out, int out_size, void* d_ws, size_t ws_size,
                              hipStream_t stream) {
    const fvec4* a = (const fvec4*)d_in[0];
    const fvec4* b = (const fvec4*)d_in[1];
    const fvec4* w = (const fvec4*)d_in[2];
    fvec4* out = (fvec4*)d_out;
    // 16,777,216 vec4 total; 8192 vec4 (8 rows) per block -> 2048 blocks.
    const int grid = out_size / (4 * 8192);
    merger_kernel<<<grid, 256, 0, stream>>>(a, b, w, out);
}

// Round 5
// 143.519 us; speedup vs baseline: 1.1268x; 1.1268x over previous
//
#include <hip/hip_runtime.h>

// out[b,s,f] = in1[b,s,f] * w[f] + in2[b,s,f] * (1 - w[f])
// B=4, S=4096, F=4096 -> 67,108,864 f32 = 16,777,216 vec4. Memory-bound.
//
// R4 post-mortem: persistent 2048-block pipeline regressed (load imbalance +
// VGPR growth); R3's flat one-shot 16384-block form self-balances. R3's
// remaining gap to roofline: each wave fully drains vmcnt once per 12 KB of
// traffic, then dies. R5 doubles the burst (2 rows/block, 16 loads in flight,
// 24 KB/wave) and orders loads a/b-pairwise so compute+store of pair i waits
// only vmcnt(14-2i) -- early stores overlap late load arrivals.

typedef float fvec4 __attribute__((ext_vector_type(4)));

__global__ __launch_bounds__(256) void merger_kernel(
    const fvec4* __restrict__ a,
    const fvec4* __restrict__ b,
    const fvec4* __restrict__ w,
    fvec4* __restrict__ out) {
    const int t = threadIdx.x;
    const int base = blockIdx.x * 2048 + t;  // 2 rows of 1024 vec4 per block

    // Weight fragments: same for both rows (row position = t + j*256).
    const fvec4 w0 = w[t];
    const fvec4 w1 = w[t + 256];
    const fvec4 w2 = w[t + 512];
    const fvec4 w3 = w[t + 768];

    const int r0 = base;          // row 0
    const int r1 = base + 1024;   // row 1

    // 16 loads issued back-to-back, a/b interleaved pairwise so the consumer
    // of pair i waits on the two oldest outstanding loads only.
    const fvec4 a00 = a[r0];        const fvec4 b00 = b[r0];
    const fvec4 a01 = a[r0 + 256];  const fvec4 b01 = b[r0 + 256];
    const fvec4 a02 = a[r0 + 512];  const fvec4 b02 = b[r0 + 512];
    const fvec4 a03 = a[r0 + 768];  const fvec4 b03 = b[r0 + 768];
    const fvec4 a10 = a[r1];        const fvec4 b10 = b[r1];
    const fvec4 a11 = a[r1 + 256];  const fvec4 b11 = b[r1 + 256];
    const fvec4 a12 = a[r1 + 512];  const fvec4 b12 = b[r1 + 512];
    const fvec4 a13 = a[r1 + 768];  const fvec4 b13 = b[r1 + 768];

    // Compute+store in load order: partial vmcnt waits, incremental drain.
    fvec4 o;
    o = a00 * w0 + b00 * (1.0f - w0); __builtin_nontemporal_store(o, &out[r0]);
    o = a01 * w1 + b01 * (1.0f - w1); __builtin_nontemporal_store(o, &out[r0 + 256]);
    o = a02 * w2 + b02 * (1.0f - w2); __builtin_nontemporal_store(o, &out[r0 + 512]);
    o = a03 * w3 + b03 * (1.0f - w3); __builtin_nontemporal_store(o, &out[r0 + 768]);
    o = a10 * w0 + b10 * (1.0f - w0); __builtin_nontemporal_store(o, &out[r1]);
    o = a11 * w1 + b11 * (1.0f - w1); __builtin_nontemporal_store(o, &out[r1 + 256]);
    o = a12 * w2 + b12 * (1.0f - w2); __builtin_nontemporal_store(o, &out[r1 + 512]);
    o = a13 * w3 + b13 * (1.0f - w3); __builtin_nontemporal_store(o, &out[r1 + 768]);
}

extern "C" void kernel_launch(void* const* d_in, const int* in_sizes, int n_in,
                              void* d_out, int out_size, void* d_ws, size_t ws_size,
                              hipStream_t stream) {
    const fvec4* a = (const fvec4*)d_in[0];
    const fvec4* b = (const fvec4*)d_in[1];
    const fvec4* w = (const fvec4*)d_in[2];
    fvec4* out = (fvec4*)d_out;
    // 16,777,216 vec4 total; 2048 vec4 (2 rows) per block -> 8192 blocks.
    const int grid = out_size / (4 * 2048);
    merger_kernel<<<grid, 256, 0, stream>>>(a, b, w, out);
}